// Round 6
// baseline (2335.836 us; speedup 1.0000x reference)
//
#include <hip/hip_runtime.h>
#include <hip/hip_bf16.h>
#include <cstdint>
#include <cstddef>

// Dan_attention on MI355X (gfx950) — R4 rewrite, R5 resubmission (R4 never
// ran: GPU acquisition timeout).
// Diagnosis of R1/R2 failures: absmax 5.375 == expected max|ref| for an
// ALL-ZERO d_out (max|N(0,1)| over 16.7M ~ 5.39). The ws guard
// (`if (ws_size < 416MB) return;`) silently skipped all launches -> ws_size
// is smaller than assumed. This version adapts to ws_size (floor 56 MiB)
// and NEVER early-returns silently (1e30 marker instead).
//
// Math: S = Q K^T = x (Wq Wk^T) x^T.  G = Wq Wk^T;  y = x G  (stored in
// d_out, rows die exactly when PV overwrites them);  S-chunk = y_chunk x^T;
// softmax per row -> P bf16 packed in-place;  out_chunk = P_chunk @ V.
// V^T (bf16) built once via transposed-store projection GEMM.
//
// ws layout: [Mb = G^T fp32 16MiB][Vt bf16 32MiB][chunk: WvT fp32 16MiB
// (setup only) / S-chunk R*32KiB].  R adaptive in {256..8192}.

typedef float  f32x4 __attribute__((ext_vector_type(4)));
typedef short  s16x8 __attribute__((ext_vector_type(8)));
typedef unsigned short u16;
typedef u16    u16x4 __attribute__((ext_vector_type(4)));

#define NROWS 8192
#define DDIM  2048

static __device__ __forceinline__ u16 f2bf(float f) {
    unsigned u = __float_as_uint(f);
    u += 0x7FFFu + ((u >> 16) & 1u);   // round-to-nearest-even
    return (u16)(u >> 16);
}
static __device__ __forceinline__ float bf2f(u16 h) {
    return __uint_as_float(((unsigned)h) << 16);
}
static __device__ __forceinline__ f32x4 mfma16(s16x8 a, s16x8 b, f32x4 c) {
    return __builtin_amdgcn_mfma_f32_16x16x32_bf16(a, b, c, 0, 0, 0);
}

// ---------------- fp32 transpose (2048x2048) ---------------------------------
__global__ __launch_bounds__(256) void transpose_f32k(const float* __restrict__ in,
                                                      float* __restrict__ op,
                                                      int rows, int cols) {
    __shared__ float t[32][33];
    const int r  = threadIdx.x >> 3;
    const int c4 = (threadIdx.x & 7) << 2;
    f32x4 v = *(const f32x4*)(in + (size_t)(blockIdx.y * 32 + r) * cols + blockIdx.x * 32 + c4);
    t[r][c4 + 0] = v[0]; t[r][c4 + 1] = v[1]; t[r][c4 + 2] = v[2]; t[r][c4 + 3] = v[3];
    __syncthreads();
    f32x4 o;
#pragma unroll
    for (int j = 0; j < 4; ++j) o[j] = t[c4 + j][r];
    *(f32x4*)(op + (size_t)(blockIdx.x * 32 + r) * rows + blockIdx.y * 32 + c4) = o;
}

// ---------------- diagnostic marker ------------------------------------------
__global__ void fill_marker(float* o, long n) {
    long i = (long)blockIdx.x * blockDim.x + threadIdx.x;
    const long stride = (long)gridDim.x * blockDim.x;
    for (; i < n; i += stride) o[i] = 1.0e30f;
}

// ---------------- universal split-bf16 B^T GEMM ------------------------------
// C[m,n] = sum_k A[m,k]*B[n,k].
// AF32=1: A fp32, split on load into NA bf16 comps; AF32=0: A = NA u16 arrays.
// Same for B. Products (i,j) with i+j<=ORD, fp32 accum.
// OUTM=0: Cf[r*ldc+c] fp32.  OUTM=1: Ct[c*ldc+r] bf16 (transposed store).
// Tile 128x128, BK=32, 256 threads = 4 waves (2x2), 4x4 16x16 frags/wave.
template<int NA, int NB, int ORD, int AF32, int BF32, int OUTM>
__global__ __launch_bounds__(256) void gemm_u(
    const void* Ap0, const void* Ap1, const void* Ap2, long lda,
    const void* Bp0, const void* Bp1, const void* Bp2, long ldb,
    float* __restrict__ Cf, u16* __restrict__ Ct, long ldc, int K)
{
    __shared__ __align__(16) u16 lds[NA + NB][128][40];  // 80B row stride: 2-way banks (free)

    const int tid  = threadIdx.x;
    const int lane = tid & 63;
    const int w    = tid >> 6;
    const int wr   = w >> 1, wc = w & 1;
    const int lrow = lane & 15, kg = lane >> 4;
    const long brow = (long)blockIdx.y * 128;
    const long bcol = (long)blockIdx.x * 128;
    const int srow = tid >> 1;
    const int sk   = (tid & 1) * 16;

    f32x4 acc[4][4];
#pragma unroll
    for (int m = 0; m < 4; ++m)
#pragma unroll
        for (int n = 0; n < 4; ++n) acc[m][n] = (f32x4){0.f, 0.f, 0.f, 0.f};

    const int nk = K / 32;
    for (int kt = 0; kt < nk; ++kt) {
        u16x4 sa[NA][4], sb[NB][4];
        if (AF32) {
            const float* pA = (const float*)Ap0 + (brow + srow) * lda + (long)kt * 32 + sk;
#pragma unroll
            for (int q = 0; q < 4; ++q) {
                f32x4 v = *(const f32x4*)(pA + q * 4);
#pragma unroll
                for (int e = 0; e < 4; ++e) {
                    float f = v[e];
                    u16 hh = f2bf(f); sa[0][q][e] = hh;
                    if (NA > 1) {
                        float r1 = f - bf2f(hh);
                        u16 mm = f2bf(r1); sa[1][q][e] = mm;
                        if (NA > 2) sa[2][q][e] = f2bf(r1 - bf2f(mm));
                    }
                }
            }
        } else {
            const u16* as[3] = {(const u16*)Ap0, (const u16*)Ap1, (const u16*)Ap2};
            const long off = (brow + srow) * lda + (long)kt * 32 + sk;
#pragma unroll
            for (int i = 0; i < NA; ++i) {
                s16x8 v0 = *(const s16x8*)(as[i] + off);
                s16x8 v1 = *(const s16x8*)(as[i] + off + 8);
                *(s16x8*)&sa[i][0] = v0;
                *(s16x8*)&sa[i][2] = v1;
            }
        }
        if (BF32) {
            const float* pB = (const float*)Bp0 + (bcol + srow) * ldb + (long)kt * 32 + sk;
#pragma unroll
            for (int q = 0; q < 4; ++q) {
                f32x4 v = *(const f32x4*)(pB + q * 4);
#pragma unroll
                for (int e = 0; e < 4; ++e) {
                    float f = v[e];
                    u16 hh = f2bf(f); sb[0][q][e] = hh;
                    if (NB > 1) {
                        float r1 = f - bf2f(hh);
                        u16 mm = f2bf(r1); sb[1][q][e] = mm;
                        if (NB > 2) sb[2][q][e] = f2bf(r1 - bf2f(mm));
                    }
                }
            }
        } else {
            const u16* bs[3] = {(const u16*)Bp0, (const u16*)Bp1, (const u16*)Bp2};
            const long off = (bcol + srow) * ldb + (long)kt * 32 + sk;
#pragma unroll
            for (int j = 0; j < NB; ++j) {
                s16x8 v0 = *(const s16x8*)(bs[j] + off);
                s16x8 v1 = *(const s16x8*)(bs[j] + off + 8);
                *(s16x8*)&sb[j][0] = v0;
                *(s16x8*)&sb[j][2] = v1;
            }
        }

        __syncthreads();   // previous iteration's LDS readers done
#pragma unroll
        for (int i = 0; i < NA; ++i)
#pragma unroll
            for (int q = 0; q < 4; ++q)
                *(u16x4*)&lds[i][srow][sk + q * 4] = sa[i][q];
#pragma unroll
        for (int j = 0; j < NB; ++j)
#pragma unroll
            for (int q = 0; q < 4; ++q)
                *(u16x4*)&lds[NA + j][srow][sk + q * 4] = sb[j][q];
        __syncthreads();

        s16x8 bfr[NB][4];
#pragma unroll
        for (int j = 0; j < NB; ++j)
#pragma unroll
            for (int n = 0; n < 4; ++n)
                bfr[j][n] = *(const s16x8*)&lds[NA + j][wc * 64 + n * 16 + lrow][kg * 8];
#pragma unroll
        for (int m = 0; m < 4; ++m) {
            s16x8 afr[NA];
#pragma unroll
            for (int i = 0; i < NA; ++i)
                afr[i] = *(const s16x8*)&lds[i][wr * 64 + m * 16 + lrow][kg * 8];
#pragma unroll
            for (int n = 0; n < 4; ++n) {
#pragma unroll
                for (int i = 0; i < NA; ++i)
#pragma unroll
                    for (int j = 0; j < NB; ++j)
                        if (i + j <= ORD)
                            acc[m][n] = mfma16(afr[i], bfr[j][n], acc[m][n]);
            }
        }
    }

    // epilogue; C/D frag layout (m89-verified): col = lane&15, row = (lane>>4)*4 + reg
#pragma unroll
    for (int m = 0; m < 4; ++m) {
#pragma unroll
        for (int n = 0; n < 4; ++n) {
            const long c = bcol + wc * 64 + n * 16 + lrow;
            if (OUTM == 0) {
#pragma unroll
                for (int reg = 0; reg < 4; ++reg) {
                    const long r = brow + wr * 64 + m * 16 + kg * 4 + reg;
                    Cf[r * ldc + c] = acc[m][n][reg];
                }
            } else {
                const long r0 = brow + wr * 64 + m * 16 + kg * 4;
                u16x4 hv;
#pragma unroll
                for (int reg = 0; reg < 4; ++reg) hv[reg] = f2bf(acc[m][n][reg]);
                *(u16x4*)(Ct + c * ldc + r0) = hv;
            }
        }
    }
}

// ---------------- row softmax, P packed in place as bf16 ---------------------
// One block per row of the S-chunk (row slot = 8192 f32 = 32KB; P bf16 fills
// the first 16KB of the slot).
__global__ __launch_bounds__(256) void softmax_rows(float* __restrict__ S) {
    __shared__ float row[NROWS];   // 32 KB
    __shared__ float red[4];
    const int tid = threadIdx.x;
    const int lane = tid & 63, wid = tid >> 6;
    float* src = S + (size_t)blockIdx.x * NROWS;

    float lmax = -3.4e38f;
    for (int i = tid * 4; i < NROWS; i += 1024) {
        f32x4 v = *(const f32x4*)(src + i);
        row[i] = v[0]; row[i + 1] = v[1]; row[i + 2] = v[2]; row[i + 3] = v[3];
        lmax = fmaxf(fmaxf(fmaxf(lmax, v[0]), v[1]), fmaxf(v[2], v[3]));
    }
#pragma unroll
    for (int off = 32; off; off >>= 1) lmax = fmaxf(lmax, __shfl_xor(lmax, off, 64));
    if (lane == 0) red[wid] = lmax;
    __syncthreads();
    const float m = fmaxf(fmaxf(red[0], red[1]), fmaxf(red[2], red[3]));
    __syncthreads();

    float lsum = 0.f;
    for (int i = tid * 4; i < NROWS; i += 1024) {
        float e0 = __expf(row[i] - m);
        float e1 = __expf(row[i + 1] - m);
        float e2 = __expf(row[i + 2] - m);
        float e3 = __expf(row[i + 3] - m);
        row[i] = e0; row[i + 1] = e1; row[i + 2] = e2; row[i + 3] = e3;
        lsum += (e0 + e1) + (e2 + e3);
    }
#pragma unroll
    for (int off = 32; off; off >>= 1) lsum += __shfl_xor(lsum, off, 64);
    if (lane == 0) red[wid] = lsum;
    __syncthreads();
    const float inv = 1.0f / ((red[0] + red[1]) + (red[2] + red[3]));

    u16* ph = (u16*)src;
    for (int i = tid * 4; i < NROWS; i += 1024) {
        u16x4 h;
#pragma unroll
        for (int j = 0; j < 4; ++j) h[j] = f2bf(row[i + j] * inv);
        *(u16x4*)(ph + i) = h;
    }
}

// -----------------------------------------------------------------------------
extern "C" void kernel_launch(void* const* d_in, const int* in_sizes, int n_in,
                              void* d_out, int out_size, void* d_ws, size_t ws_size,
                              hipStream_t stream) {
    const float* x  = (const float*)d_in[0];
    const float* wk = (const float*)d_in[1];
    const float* wv = (const float*)d_in[2];
    const float* wq = (const float*)d_in[3];
    float* out = (float*)d_out;
    char*  ws  = (char*)d_ws;
    const size_t MiB = 1024ull * 1024ull;

    // adaptive chunk rows R: ws = 48MiB fixed + max(16MiB, R*32KiB)
    long R = 0;
    const size_t fixed = 48 * MiB;
    if      (ws_size >= fixed + 256 * MiB) R = 8192;
    else if (ws_size >= fixed + 128 * MiB) R = 4096;
    else if (ws_size >= fixed +  64 * MiB) R = 2048;
    else if (ws_size >= fixed +  32 * MiB) R = 1024;
    else if (ws_size >= fixed +  16 * MiB) R = 512;
    else if (ws_size >= fixed +   8 * MiB) R = 256;
    if (R == 0) {   // ws too small even for the minimal plan -> loud marker
        fill_marker<<<dim3(2048), dim3(256), 0, stream>>>(out, (long)NROWS * DDIM);
        return;
    }

    float* Mb  = (float*)(ws);             // G^T fp32 [2048][2048], 16 MiB
    u16*   Vt  = (u16*)(ws + 16 * MiB);    // V^T bf16 [2048][8192], 32 MiB
    char*  cb  = ws + 48 * MiB;
    float* WvT = (float*)cb;               // fp32 [2048][2048] (dead before chunks)
    float* Sch = (float*)cb;               // S-chunk fp32 [R][8192]
    float* y   = out;                      // y = x@G lives in d_out (overlay)

    const dim3 b256(256);

    // 1. Mb[v][u] = sum_a wk[v][a]*wq[u][a]  ( = G^T, G = Wq Wk^T ), 6-product
    gemm_u<3, 3, 2, 1, 1, 0><<<dim3(16, 16), b256, 0, stream>>>(
        wk, nullptr, nullptr, (long)DDIM, wq, nullptr, nullptr, (long)DDIM,
        Mb, nullptr, (long)DDIM, DDIM);

    // 2. V^T: WvT = wv^T;  Vt[c][r] = (x@Wv)[r][c]  (3-product, bf16 store)
    transpose_f32k<<<dim3(64, 64), b256, 0, stream>>>(wv, WvT, DDIM, DDIM);
    gemm_u<2, 2, 1, 1, 1, 1><<<dim3(16, 64), b256, 0, stream>>>(
        x, nullptr, nullptr, (long)DDIM, WvT, nullptr, nullptr, (long)DDIM,
        nullptr, Vt, (long)NROWS, DDIM);

    // 3. y = x@G  (B = Mb rows = G^T rows), fp32 into d_out
    gemm_u<2, 2, 1, 1, 1, 0><<<dim3(16, 64), b256, 0, stream>>>(
        x, nullptr, nullptr, (long)DDIM, Mb, nullptr, nullptr, (long)DDIM,
        y, nullptr, (long)DDIM, DDIM);

    // 4. per row-chunk: S = y_c x^T -> softmax -> out_c = P V
    const long nc = NROWS / R;
    for (long c = 0; c < nc; ++c) {
        float* yc = y   + (size_t)c * R * DDIM;
        float* oc = out + (size_t)c * R * DDIM;
        gemm_u<2, 2, 1, 1, 1, 0><<<dim3(64, R / 128), b256, 0, stream>>>(
            yc, nullptr, nullptr, (long)DDIM, x, nullptr, nullptr, (long)DDIM,
            Sch, nullptr, (long)NROWS, DDIM);
        softmax_rows<<<dim3(R), b256, 0, stream>>>(Sch);
        gemm_u<1, 1, 0, 0, 0, 0><<<dim3(16, R / 128), b256, 0, stream>>>(
            (const u16*)Sch, nullptr, nullptr, (long)(2 * NROWS),
            Vt, nullptr, nullptr, (long)NROWS,
            oc, nullptr, (long)DDIM, NROWS);
    }
}

// Round 7
// 1878.412 us; speedup vs baseline: 1.2435x; 1.2435x over previous
//
#include <hip/hip_runtime.h>
#include <hip/hip_bf16.h>
#include <cstdint>
#include <cstddef>

// Dan_attention on MI355X (gfx950) — R6: packed-operand GEMMs.
// R5 passed (2335us, absmax .031). Profile: VALUBusy 56% > MfmaUtil 34%,
// 6.7e7 LDS bank conflicts -> on-load f32->bf16 split VALU + 8-way-conflicted
// ds_writes dominate. Fix: pre-split all big-GEMM operands into bf16 hi/mid
// stored in MFMA-fragment-order packed tiles (16rx32k subtile = 64 lanes x
// 16B in lane order), staged via global_load_lds(width=16) into linear LDS;
// fragment ds_read_b128 at lane*16B is conflict-free. PV/G keep reg-staging
// with pad 36 u16 (18 dwords, gcd(18,32)=2 -> ~2-way, free).
//
// Pipeline: split-pack x -> G^T=wk.wq^T (packed out) -> y=x@G (gemm_pk,
// packed out into d_out overlay, per-chunk) -> wv^T packed -> Vt=(x@Wv)^T
// (gemm_pk) -> per chunk: S=y_c x^T (gemm_pk) -> softmax (P bf16 in place)
// -> out_c = P@V (gemm_u).
// ws: [xh 32][xm 32][Vt 32][cb: max(16MiB, R*32KiB)]; floor 112 MiB.

typedef float  f32x4 __attribute__((ext_vector_type(4)));
typedef short  s16x8 __attribute__((ext_vector_type(8)));
typedef unsigned short u16;
typedef u16    u16x4 __attribute__((ext_vector_type(4)));
typedef u16    u16x8 __attribute__((ext_vector_type(8)));

#define NROWS 8192
#define DDIM  2048

static __device__ __forceinline__ u16 f2bf(float f) {
    unsigned u = __float_as_uint(f);
    u += 0x7FFFu + ((u >> 16) & 1u);   // round-to-nearest-even
    return (u16)(u >> 16);
}
static __device__ __forceinline__ float bf2f(u16 h) {
    return __uint_as_float(((unsigned)h) << 16);
}
static __device__ __forceinline__ f32x4 mfma16(s16x8 a, s16x8 b, f32x4 c) {
    return __builtin_amdgcn_mfma_f32_16x16x32_bf16(a, b, c, 0, 0, 0);
}
static __device__ __forceinline__ void gload16(const void* g, void* l) {
    __builtin_amdgcn_global_load_lds(
        (const __attribute__((address_space(1))) void*)g,
        (__attribute__((address_space(3))) void*)l, 16, 0, 0);
}

// Packed layout PK(Rows,K=2048): chunk index i = (rt*64 + kt)*64 + kg*16 + lrow
// holds Z[rt*16+lrow][kt*32+kg*8 .. +8] as 8 u16 at offset i*8.  A wave's
// 16x32 MFMA fragment tile = chunks [lane 0..63] contiguous (1 KiB).

// ---------------- x -> packed bf16 hi/mid -------------------------------------
__global__ __launch_bounds__(256) void split2_pack(const float* __restrict__ x,
                                                   u16* __restrict__ xh,
                                                   u16* __restrict__ xm) {
    const long i   = (long)blockIdx.x * 256 + threadIdx.x;   // chunk index
    const int  sub = (int)(i & 63);
    const long tk  = i >> 6;
    const int  kt  = (int)(tk & 63);
    const long rt  = tk >> 6;
    const long row = rt * 16 + (sub & 15);
    const int  k0  = kt * 32 + (sub >> 4) * 8;
    const float* p = x + row * DDIM + k0;
    f32x4 v0 = *(const f32x4*)p, v1 = *(const f32x4*)(p + 4);
    u16x8 h, m;
#pragma unroll
    for (int j = 0; j < 8; ++j) {
        float f = (j < 4) ? v0[j] : v1[j - 4];
        u16 hh = f2bf(f); h[j] = hh; m[j] = f2bf(f - bf2f(hh));
    }
    *(u16x8*)(xh + i * 8) = h;
    *(u16x8*)(xm + i * 8) = m;
}

// ---------------- wv -> transposed packed bf16 hi/mid ------------------------
__global__ __launch_bounds__(256) void twvpack(const float* __restrict__ wv,
                                               u16* __restrict__ th,
                                               u16* __restrict__ tm) {
    const long i   = (long)blockIdx.x * 256 + threadIdx.x;
    const int  sub = (int)(i & 63);
    const long tk  = i >> 6;
    const int  kt  = (int)(tk & 63);
    const long rt  = tk >> 6;
    const long rowp = rt * 16 + (sub & 15);      // WvT row (= wv col)
    const int  k0   = kt * 32 + (sub >> 4) * 8;  // WvT col (= wv row)
    u16x8 h, m;
#pragma unroll
    for (int j = 0; j < 8; ++j) {
        float f = wv[(long)(k0 + j) * DDIM + rowp];
        u16 hh = f2bf(f); h[j] = hh; m[j] = f2bf(f - bf2f(hh));
    }
    *(u16x8*)(th + i * 8) = h;
    *(u16x8*)(tm + i * 8) = m;
}

// ---------------- diagnostic marker ------------------------------------------
__global__ void fill_marker(float* o, long n) {
    long i = (long)blockIdx.x * blockDim.x + threadIdx.x;
    const long stride = (long)gridDim.x * blockDim.x;
    for (; i < n; i += stride) o[i] = 1.0e30f;
}

// ---------------- packed-operand GEMM (K=2048 fixed) -------------------------
// C[m,n] = sum_k A[m,k]B[n,k], A/B 2-comp packed, 3 products (hh,hm,mh).
// 128x128 tile, BK=32, 4 waves; staging via global_load_lds, LDS linear.
// OUTM 0: Cf[r*ldc+c] fp32.  1: Ct[c*ldc+r] bf16 (transposed).
// 2: packed-split store (chunked PK, rshift = log2(chunk rows)).
template<int OUTM>
__global__ __launch_bounds__(256) void gemm_pk(
    const u16* __restrict__ Ah, const u16* __restrict__ Am,
    const u16* __restrict__ Bh, const u16* __restrict__ Bm,
    float* __restrict__ Cf, u16* __restrict__ Ct, long ldc, int rshift)
{
    __shared__ __align__(16) u16 lds[4][8][512];   // 32 KiB: Ah,Am,Bh,Bm tiles

    const int tid = threadIdx.x, lane = tid & 63, w = tid >> 6;
    const int wr = w >> 1, wc = w & 1;
    const long bx = blockIdx.x, by = blockIdx.y;

    // wave w stages comp-op w (0=Ah 1=Am 2=Bh 3=Bm), 8 subtiles each
    const u16* t0 = (w & 1) ? Am : Ah;
    const u16* t1 = (w & 1) ? Bm : Bh;
    const u16* gb = (w & 2) ? t1 : t0;
    const long tb = ((w & 2) ? bx : by) * 8;
    u16* lb = (u16*)&lds[0][0][0] + (long)w * 8 * 512;

    f32x4 acc[4][4];
#pragma unroll
    for (int m = 0; m < 4; ++m)
#pragma unroll
        for (int n = 0; n < 4; ++n) acc[m][n] = (f32x4){0.f, 0.f, 0.f, 0.f};

    for (int kt = 0; kt < 64; ++kt) {
        __syncthreads();                                   // prev reads done
        const u16* gt = gb + (tb * 64 + kt) * 512 + lane * 8;
#pragma unroll
        for (int t = 0; t < 8; ++t)
            gload16(gt + (long)t * 32768, lb + t * 512);
        __syncthreads();                                   // vmcnt drained -> LDS ready

        s16x8 bh[4], bm[4];
#pragma unroll
        for (int n = 0; n < 4; ++n) {
            bh[n] = *(const s16x8*)&lds[2][wc * 4 + n][lane * 8];
            bm[n] = *(const s16x8*)&lds[3][wc * 4 + n][lane * 8];
        }
#pragma unroll
        for (int m = 0; m < 4; ++m) {
            s16x8 ah = *(const s16x8*)&lds[0][wr * 4 + m][lane * 8];
            s16x8 am = *(const s16x8*)&lds[1][wr * 4 + m][lane * 8];
#pragma unroll
            for (int n = 0; n < 4; ++n) {
                acc[m][n] = mfma16(ah, bh[n], acc[m][n]);
                acc[m][n] = mfma16(ah, bm[n], acc[m][n]);
                acc[m][n] = mfma16(am, bh[n], acc[m][n]);
            }
        }
    }

    // epilogue; C/D layout (m89): col = lane&15, row = (lane>>4)*4 + reg
    const int lrow = lane & 15, kg = lane >> 4;
#pragma unroll
    for (int m = 0; m < 4; ++m) {
#pragma unroll
        for (int n = 0; n < 4; ++n) {
            const long c  = bx * 128 + wc * 64 + n * 16 + lrow;
            const long r0 = by * 128 + wr * 64 + m * 16 + kg * 4;
            if (OUTM == 0) {
#pragma unroll
                for (int reg = 0; reg < 4; ++reg)
                    Cf[(r0 + reg) * ldc + c] = acc[m][n][reg];
            } else if (OUTM == 1) {
                u16x4 hv;
#pragma unroll
                for (int reg = 0; reg < 4; ++reg) hv[reg] = f2bf(acc[m][n][reg]);
                *(u16x4*)(Ct + c * ldc + r0) = hv;
            } else {
#pragma unroll
                for (int reg = 0; reg < 4; ++reg) {
                    const long r = r0 + reg;
                    const float v = acc[m][n][reg];
                    const u16 hh = f2bf(v);
                    const u16 mm = f2bf(v - bf2f(hh));
                    const long base = (r >> rshift) << (rshift + 12);
                    const long off  = ((((r & ((1L << rshift) - 1)) >> 4) * 64 + (c >> 5)) * 64
                                       + ((c & 31) >> 3) * 16 + (r & 15)) * 8 + (c & 7);
                    Ct[base + off] = hh;
                    Ct[base + (1L << (rshift + 11)) + off] = mm;
                }
            }
        }
    }
}

// ---------------- reg-staged split GEMM (G, PV) ------------------------------
// Pad 36 u16 (72 B = 18 dwords, gcd(18,32)=2 -> ~2-way banks both rd & wr).
template<int NA, int NB, int ORD, int AF32, int BF32, int OUTM>
__global__ __launch_bounds__(256) void gemm_u(
    const void* Ap0, const void* Ap1, const void* Ap2, long lda,
    const void* Bp0, const void* Bp1, const void* Bp2, long ldb,
    float* __restrict__ Cf, u16* __restrict__ Ct, long ldc, int K, int rshift)
{
    __shared__ __align__(16) u16 lds[NA + NB][128][36];

    const int tid  = threadIdx.x;
    const int lane = tid & 63;
    const int w    = tid >> 6;
    const int wr   = w >> 1, wc = w & 1;
    const int lrow = lane & 15, kg = lane >> 4;
    const long brow = (long)blockIdx.y * 128;
    const long bcol = (long)blockIdx.x * 128;
    const int srow = tid >> 1;
    const int sk   = (tid & 1) * 16;

    f32x4 acc[4][4];
#pragma unroll
    for (int m = 0; m < 4; ++m)
#pragma unroll
        for (int n = 0; n < 4; ++n) acc[m][n] = (f32x4){0.f, 0.f, 0.f, 0.f};

    const int nk = K / 32;
    for (int kt = 0; kt < nk; ++kt) {
        u16x4 sa[NA][4], sb[NB][4];
        if (AF32) {
            const float* pA = (const float*)Ap0 + (brow + srow) * lda + (long)kt * 32 + sk;
#pragma unroll
            for (int q = 0; q < 4; ++q) {
                f32x4 v = *(const f32x4*)(pA + q * 4);
#pragma unroll
                for (int e = 0; e < 4; ++e) {
                    float f = v[e];
                    u16 hh = f2bf(f); sa[0][q][e] = hh;
                    if (NA > 1) sa[1][q][e] = f2bf(f - bf2f(hh));
                }
            }
        } else {
            const u16* as0 = (const u16*)Ap0;
            const long off = (brow + srow) * lda + (long)kt * 32 + sk;
            s16x8 v0 = *(const s16x8*)(as0 + off);
            s16x8 v1 = *(const s16x8*)(as0 + off + 8);
            *(s16x8*)&sa[0][0] = v0;
            *(s16x8*)&sa[0][2] = v1;
        }
        if (BF32) {
            const float* pB = (const float*)Bp0 + (bcol + srow) * ldb + (long)kt * 32 + sk;
#pragma unroll
            for (int q = 0; q < 4; ++q) {
                f32x4 v = *(const f32x4*)(pB + q * 4);
#pragma unroll
                for (int e = 0; e < 4; ++e) {
                    float f = v[e];
                    u16 hh = f2bf(f); sb[0][q][e] = hh;
                    if (NB > 1) sb[1][q][e] = f2bf(f - bf2f(hh));
                }
            }
        } else {
            const u16* bs0 = (const u16*)Bp0;
            const long off = (bcol + srow) * ldb + (long)kt * 32 + sk;
            s16x8 v0 = *(const s16x8*)(bs0 + off);
            s16x8 v1 = *(const s16x8*)(bs0 + off + 8);
            *(s16x8*)&sb[0][0] = v0;
            *(s16x8*)&sb[0][2] = v1;
        }

        __syncthreads();
#pragma unroll
        for (int i = 0; i < NA; ++i)
#pragma unroll
            for (int q = 0; q < 4; ++q)
                *(u16x4*)&lds[i][srow][sk + q * 4] = sa[i][q];
#pragma unroll
        for (int j = 0; j < NB; ++j)
#pragma unroll
            for (int q = 0; q < 4; ++q)
                *(u16x4*)&lds[NA + j][srow][sk + q * 4] = sb[j][q];
        __syncthreads();

        s16x8 bfr[NB][4];
#pragma unroll
        for (int j = 0; j < NB; ++j)
#pragma unroll
            for (int n = 0; n < 4; ++n)
                bfr[j][n] = *(const s16x8*)&lds[NA + j][wc * 64 + n * 16 + lrow][kg * 8];
#pragma unroll
        for (int m = 0; m < 4; ++m) {
            s16x8 afr[NA];
#pragma unroll
            for (int i = 0; i < NA; ++i)
                afr[i] = *(const s16x8*)&lds[i][wr * 64 + m * 16 + lrow][kg * 8];
#pragma unroll
            for (int n = 0; n < 4; ++n) {
#pragma unroll
                for (int i = 0; i < NA; ++i)
#pragma unroll
                    for (int j = 0; j < NB; ++j)
                        if (i + j <= ORD)
                            acc[m][n] = mfma16(afr[i], bfr[j][n], acc[m][n]);
            }
        }
    }

#pragma unroll
    for (int m = 0; m < 4; ++m) {
#pragma unroll
        for (int n = 0; n < 4; ++n) {
            const long c  = bcol + wc * 64 + n * 16 + lrow;
            const long r0 = brow + wr * 64 + m * 16 + kg * 4;
            if (OUTM == 0) {
#pragma unroll
                for (int reg = 0; reg < 4; ++reg)
                    Cf[(r0 + reg) * ldc + c] = acc[m][n][reg];
            } else if (OUTM == 1) {
                u16x4 hv;
#pragma unroll
                for (int reg = 0; reg < 4; ++reg) hv[reg] = f2bf(acc[m][n][reg]);
                *(u16x4*)(Ct + c * ldc + r0) = hv;
            } else {
#pragma unroll
                for (int reg = 0; reg < 4; ++reg) {
                    const long r = r0 + reg;
                    const float v = acc[m][n][reg];
                    const u16 hh = f2bf(v);
                    const u16 mm = f2bf(v - bf2f(hh));
                    const long base = (r >> rshift) << (rshift + 12);
                    const long off  = ((((r & ((1L << rshift) - 1)) >> 4) * 64 + (c >> 5)) * 64
                                       + ((c & 31) >> 3) * 16 + (r & 15)) * 8 + (c & 7);
                    Ct[base + off] = hh;
                    Ct[base + (1L << (rshift + 11)) + off] = mm;
                }
            }
        }
    }
}

// ---------------- row softmax, P packed in place as bf16 ---------------------
__global__ __launch_bounds__(256) void softmax_rows(float* __restrict__ S) {
    __shared__ float row[NROWS];   // 32 KB
    __shared__ float red[4];
    const int tid = threadIdx.x;
    const int lane = tid & 63, wid = tid >> 6;
    float* src = S + (size_t)blockIdx.x * NROWS;

    float lmax = -3.4e38f;
    for (int i = tid * 4; i < NROWS; i += 1024) {
        f32x4 v = *(const f32x4*)(src + i);
        row[i] = v[0]; row[i + 1] = v[1]; row[i + 2] = v[2]; row[i + 3] = v[3];
        lmax = fmaxf(fmaxf(fmaxf(lmax, v[0]), v[1]), fmaxf(v[2], v[3]));
    }
#pragma unroll
    for (int off = 32; off; off >>= 1) lmax = fmaxf(lmax, __shfl_xor(lmax, off, 64));
    if (lane == 0) red[wid] = lmax;
    __syncthreads();
    const float m = fmaxf(fmaxf(red[0], red[1]), fmaxf(red[2], red[3]));
    __syncthreads();

    float lsum = 0.f;
    for (int i = tid * 4; i < NROWS; i += 1024) {
        float e0 = __expf(row[i] - m);
        float e1 = __expf(row[i + 1] - m);
        float e2 = __expf(row[i + 2] - m);
        float e3 = __expf(row[i + 3] - m);
        row[i] = e0; row[i + 1] = e1; row[i + 2] = e2; row[i + 3] = e3;
        lsum += (e0 + e1) + (e2 + e3);
    }
#pragma unroll
    for (int off = 32; off; off >>= 1) lsum += __shfl_xor(lsum, off, 64);
    if (lane == 0) red[wid] = lsum;
    __syncthreads();
    const float inv = 1.0f / ((red[0] + red[1]) + (red[2] + red[3]));

    u16* ph = (u16*)src;   // P bf16 fills first 16 KB of the 32 KB row slot
    for (int i = tid * 4; i < NROWS; i += 1024) {
        u16x4 h;
#pragma unroll
        for (int j = 0; j < 4; ++j) h[j] = f2bf(row[i + j] * inv);
        *(u16x4*)(ph + i) = h;
    }
}

// -----------------------------------------------------------------------------
extern "C" void kernel_launch(void* const* d_in, const int* in_sizes, int n_in,
                              void* d_out, int out_size, void* d_ws, size_t ws_size,
                              hipStream_t stream) {
    const float* x  = (const float*)d_in[0];
    const float* wk = (const float*)d_in[1];
    const float* wv = (const float*)d_in[2];
    const float* wq = (const float*)d_in[3];
    float* out = (float*)d_out;
    char*  ws  = (char*)d_ws;
    const size_t MiB = 1024ull * 1024ull;

    long R = 0;
    if      (ws_size >= 352 * MiB) R = 8192;
    else if (ws_size >= 224 * MiB) R = 4096;
    else if (ws_size >= 160 * MiB) R = 2048;
    else if (ws_size >= 128 * MiB) R = 1024;
    else if (ws_size >= 112 * MiB) R = 512;
    if (R == 0) {
        fill_marker<<<dim3(2048), dim3(256), 0, stream>>>(out, (long)NROWS * DDIM);
        return;
    }
    int rs = 0; while ((1L << rs) < R) ++rs;

    u16* xh = (u16*)ws;
    u16* xm = (u16*)(ws + 32 * MiB);
    u16* Vt = (u16*)(ws + 64 * MiB);
    char* cb = ws + 96 * MiB;
    u16* Gh  = (u16*)cb;  u16* Gm  = Gh  + (long)DDIM * DDIM;
    u16* Wvh = (u16*)cb;  u16* Wvm = Wvh + (long)DDIM * DDIM;
    float* Sch = (float*)cb;
    u16* ypk = (u16*)out;            // y packed (per-chunk) overlays d_out

    const dim3 b256(256);

    // 1. x -> packed hi/mid
    split2_pack<<<dim3(8192), b256, 0, stream>>>(x, xh, xm);

    // 2. G^T = wk.wq^T, packed-split out (Rchunk=2048 -> single chunk)
    gemm_u<2, 2, 1, 1, 1, 2><<<dim3(16, 16), b256, 0, stream>>>(
        wk, nullptr, nullptr, (long)DDIM, wq, nullptr, nullptr, (long)DDIM,
        nullptr, Gh, (long)DDIM, DDIM, 11);

    // 3. y = x@G, packed-split into d_out overlay (chunked by R)
    gemm_pk<2><<<dim3(16, 64), b256, 0, stream>>>(xh, xm, Gh, Gm,
                                                  nullptr, ypk, (long)DDIM, rs);

    // 4. wv^T packed (overwrites dead G), then Vt = (x@Wv)^T bf16
    twvpack<<<dim3(2048), b256, 0, stream>>>(wv, Wvh, Wvm);
    gemm_pk<1><<<dim3(16, 64), b256, 0, stream>>>(xh, xm, Wvh, Wvm,
                                                  nullptr, Vt, (long)NROWS, 0);

    // 5. per chunk: S = y_c x^T -> softmax -> out_c = P V
    const long nc = NROWS / R;
    for (long c = 0; c < nc; ++c) {
        const u16* Ahc = ypk + c * (R << 12);
        gemm_pk<0><<<dim3(64, R / 128), b256, 0, stream>>>(
            Ahc, Ahc + R * 2048, xh, xm, Sch, nullptr, (long)NROWS, 0);
        softmax_rows<<<dim3(R), b256, 0, stream>>>(Sch);
        gemm_u<1, 1, 0, 0, 0, 0><<<dim3(16, R / 128), b256, 0, stream>>>(
            (const u16*)Sch, nullptr, nullptr, (long)(2 * NROWS),
            Vt, nullptr, nullptr, (long)NROWS,
            out + (size_t)c * R * DDIM, nullptr, (long)DDIM, NROWS, 0);
    }
}